// Round 1
// baseline (287.107 us; speedup 1.0000x reference)
//
#include <hip/hip_runtime.h>
#include <math.h>

#define BB 8
#define PP 10
#define SS 160
#define FXD 11
#define DD 64
#define DFF 256
#define NROW (BB*PP*SS)   /* 12800 */
#define NBP  (BB*PP)      /* 80 */

// d_out layout (floats): pred | pred_resampl | K | V | R | attn
#define OFF_PRED  0
#define OFF_PREDR 12800
#define OFF_K     25600
#define OFF_V     844800
#define OFF_R     1664000
#define OFF_ATTN  2483200

__device__ __forceinline__ float wred_sum(float v){
#pragma unroll
  for (int m = 32; m >= 1; m >>= 1) v += __shfl_xor(v, m, 64);
  return v;
}
__device__ __forceinline__ float wred_max(float v){
#pragma unroll
  for (int m = 32; m >= 1; m >>= 1) v = fmaxf(v, __shfl_xor(v, m, 64));
  return v;
}

// x = (inputs @ W_proj + b_proj) * 8
__global__ __launch_bounds__(256) void k_proj(const float* __restrict__ inp,
                                              const float* __restrict__ Wp,
                                              const float* __restrict__ bp,
                                              float* __restrict__ x){
  int idx = blockIdx.x * 256 + threadIdx.x;     // over NROW*64
  int row = idx >> 6, d = idx & 63;
  float acc = bp[d];
#pragma unroll
  for (int f = 0; f < FXD; ++f) acc += inp[row * FXD + f] * Wp[f * DD + d];
  x[idx] = acc * 8.0f;
}

// Q,K,V = x @ W{q,k,v} + b : tiled 64-row GEMM, 3 weights sequentially
__global__ __launch_bounds__(256) void k_qkv(const float* __restrict__ x,
    const float* __restrict__ Wq, const float* __restrict__ bq,
    const float* __restrict__ Wk, const float* __restrict__ bk,
    const float* __restrict__ Wv, const float* __restrict__ bv,
    float* __restrict__ Q, float* __restrict__ Kc, float* __restrict__ Vc){
  __shared__ float xs[64 * 65];
  __shared__ float wsb[64 * 64];
  int tid = threadIdx.x;
  int row0 = blockIdx.x * 64;
  for (int i = tid; i < 4096; i += 256) xs[(i >> 6) * 65 + (i & 63)] = x[row0 * 64 + i];
  const float* Wt[3] = {Wq, Wk, Wv};
  const float* bt[3] = {bq, bk, bv};
  float* Ot[3] = {Q, Kc, Vc};
  int tc = tid & 15, tr = tid >> 4;
  for (int w = 0; w < 3; ++w){
    __syncthreads();                               // xs visible; wsb readers done
    for (int i = tid; i < 4096; i += 256) wsb[i] = Wt[w][i];
    __syncthreads();
    float acc[4][4] = {};
    for (int k = 0; k < 64; ++k){
      float a[4];
#pragma unroll
      for (int i = 0; i < 4; ++i) a[i] = xs[(tr * 4 + i) * 65 + k];
      float4 b4 = *(const float4*)&wsb[k * 64 + tc * 4];
#pragma unroll
      for (int i = 0; i < 4; ++i){
        acc[i][0] += a[i] * b4.x; acc[i][1] += a[i] * b4.y;
        acc[i][2] += a[i] * b4.z; acc[i][3] += a[i] * b4.w;
      }
    }
    float4 bias = *(const float4*)&bt[w][tc * 4];
#pragma unroll
    for (int i = 0; i < 4; ++i){
      float4 o;
      o.x = acc[i][0] + bias.x; o.y = acc[i][1] + bias.y;
      o.z = acc[i][2] + bias.z; o.w = acc[i][3] + bias.w;
      *(float4*)&Ot[w][(row0 + tr * 4 + i) * 64 + tc * 4] = o;
    }
  }
}

// causal logits + softmax -> attn (full rows incl. zeros). one block per (b,p)
__global__ __launch_bounds__(256) void k_attn_logits(const float* __restrict__ Q,
                                                     const float* __restrict__ Kc,
                                                     float* __restrict__ attn){
  __shared__ float ks[SS * 65];
  int tid = threadIdx.x, bp = blockIdx.x;
  const float* Kb = Kc + bp * (SS * DD);
  for (int i = tid; i < SS * DD; i += 256) ks[(i >> 6) * 65 + (i & 63)] = Kb[i];
  __syncthreads();
  int lane = tid & 63, wid = tid >> 6;
  const float* Qb = Q + bp * (SS * DD);
  float* Ab = attn + bp * (SS * SS);
  int s0 = lane, s1 = lane + 64, s2 = lane + 128;
  int a0 = s0 * 65, a1 = s1 * 65, a2 = (s2 < SS ? s2 : 0) * 65;
  for (int g = wid; g < SS / 4; g += 4){
    int t0 = g * 4;
    float acc[4][3] = {};
    const float* q0 = &Qb[(t0 + 0) * DD];
    const float* q1 = &Qb[(t0 + 1) * DD];
    const float* q2 = &Qb[(t0 + 2) * DD];
    const float* q3 = &Qb[(t0 + 3) * DD];
    for (int e = 0; e < 64; ++e){
      float k0 = ks[a0 + e], k1 = ks[a1 + e], k2 = ks[a2 + e];
      float qe0 = q0[e], qe1 = q1[e], qe2 = q2[e], qe3 = q3[e];
      acc[0][0] += qe0 * k0; acc[0][1] += qe0 * k1; acc[0][2] += qe0 * k2;
      acc[1][0] += qe1 * k0; acc[1][1] += qe1 * k1; acc[1][2] += qe1 * k2;
      acc[2][0] += qe2 * k0; acc[2][1] += qe2 * k1; acc[2][2] += qe2 * k2;
      acc[3][0] += qe3 * k0; acc[3][1] += qe3 * k1; acc[3][2] += qe3 * k2;
    }
#pragma unroll
    for (int tt = 0; tt < 4; ++tt){
      int t = t0 + tt;
      bool v0 = (s0 <= t), v1 = (s1 <= t), v2 = (s2 <= t) && (s2 < SS);
      float l0 = v0 ? acc[tt][0] * 0.125f : -INFINITY;
      float l1 = v1 ? acc[tt][1] * 0.125f : -INFINITY;
      float l2 = v2 ? acc[tt][2] * 0.125f : -INFINITY;
      float m = wred_max(fmaxf(l0, fmaxf(l1, l2)));
      float e0 = v0 ? __expf(l0 - m) : 0.0f;
      float e1 = v1 ? __expf(l1 - m) : 0.0f;
      float e2 = v2 ? __expf(l2 - m) : 0.0f;
      float inv = 1.0f / wred_sum(e0 + e1 + e2);
      float* Arow = &Ab[t * SS];
      Arow[s0] = e0 * inv;
      Arow[s1] = e1 * inv;
      if (s2 < SS) Arow[s2] = e2 * inv;
    }
  }
}

// Z = attn @ V. one block per (b,p); lane = d
__global__ __launch_bounds__(256) void k_attn_z(const float* __restrict__ attn,
                                                const float* __restrict__ Vc,
                                                float* __restrict__ Z){
  __shared__ float vs[SS * 65];
  int tid = threadIdx.x, bp = blockIdx.x;
  const float* Vb = Vc + bp * (SS * DD);
  for (int i = tid; i < SS * DD; i += 256) vs[(i >> 6) * 65 + (i & 63)] = Vb[i];
  __syncthreads();
  int lane = tid & 63, wid = tid >> 6;
  const float* Ab = attn + bp * (SS * SS);
  float* Zb = Z + bp * (SS * DD);
  for (int g = wid; g < SS / 4; g += 4){
    int t0 = g * 4;
    float z0 = 0, z1 = 0, z2 = 0, z3 = 0;
    const float* p0 = &Ab[(t0 + 0) * SS];
    const float* p1 = &Ab[(t0 + 1) * SS];
    const float* p2 = &Ab[(t0 + 2) * SS];
    const float* p3 = &Ab[(t0 + 3) * SS];
    int smax = t0 + 4;                       // rows are zero beyond their t
    for (int s = 0; s < smax; ++s){
      float v = vs[s * 65 + lane];
      z0 += p0[s] * v; z1 += p1[s] * v; z2 += p2[s] * v; z3 += p3[s] * v;
    }
    Zb[(t0 + 0) * DD + lane] = z0;
    Zb[(t0 + 1) * DD + lane] = z1;
    Zb[(t0 + 2) * DD + lane] = z2;
    Zb[(t0 + 3) * DD + lane] = z3;
  }
}

// Wo + residual + LN1 + FFN + residual + LN2 -> R, pred, pred_resampl
__global__ __launch_bounds__(256) void k_post(const float* __restrict__ Z,
    const float* __restrict__ x,
    const float* __restrict__ Wo, const float* __restrict__ bo,
    const float* __restrict__ g1, const float* __restrict__ b1l,
    const float* __restrict__ W1, const float* __restrict__ b1,
    const float* __restrict__ W2, const float* __restrict__ b2,
    const float* __restrict__ g2, const float* __restrict__ b2l,
    const float* __restrict__ Wf, const float* __restrict__ bf,
    float* __restrict__ Rout, float* __restrict__ pred, float* __restrict__ predr){
  __shared__ float hs[64 * 65];   // zo tile / A-chunk / r0 tile (reused)
  __shared__ float os[64 * 65];   // LN1 output ("out"), kept for residual
  __shared__ float wsb[64 * 64];  // staged weight chunk
  int tid = threadIdx.x;
  int row0 = blockIdx.x * 64;
  int tc = tid & 15, tr = tid >> 4;
  int lane = tid & 63, wid = tid >> 6;

  // ---- zo = Z @ Wo + bo + x ----
  for (int i = tid; i < 4096; i += 256) hs[(i >> 6) * 65 + (i & 63)] = Z[row0 * 64 + i];
  for (int i = tid; i < 4096; i += 256) wsb[i] = Wo[i];
  __syncthreads();
  float acc[4][4] = {};
  for (int k = 0; k < 64; ++k){
    float a[4];
#pragma unroll
    for (int i = 0; i < 4; ++i) a[i] = hs[(tr * 4 + i) * 65 + k];
    float4 b4 = *(const float4*)&wsb[k * 64 + tc * 4];
#pragma unroll
    for (int i = 0; i < 4; ++i){
      acc[i][0] += a[i] * b4.x; acc[i][1] += a[i] * b4.y;
      acc[i][2] += a[i] * b4.z; acc[i][3] += a[i] * b4.w;
    }
  }
  float4 bo4 = *(const float4*)&bo[tc * 4];
#pragma unroll
  for (int i = 0; i < 4; ++i){
    float4 xr = *(const float4*)&x[(row0 + tr * 4 + i) * 64 + tc * 4];
    acc[i][0] += bo4.x + xr.x; acc[i][1] += bo4.y + xr.y;
    acc[i][2] += bo4.z + xr.z; acc[i][3] += bo4.w + xr.w;
  }
  __syncthreads();                 // done reading hs(Z)
#pragma unroll
  for (int i = 0; i < 4; ++i){
    hs[(tr * 4 + i) * 65 + tc * 4 + 0] = acc[i][0];
    hs[(tr * 4 + i) * 65 + tc * 4 + 1] = acc[i][1];
    hs[(tr * 4 + i) * 65 + tc * 4 + 2] = acc[i][2];
    hs[(tr * 4 + i) * 65 + tc * 4 + 3] = acc[i][3];
  }
  __syncthreads();

  // ---- LN1 -> os ----
  for (int r = wid; r < 64; r += 4){
    float h = hs[r * 65 + lane];
    float mu = wred_sum(h) * (1.0f / 64.0f);
    float dv = h - mu;
    float var = wred_sum(dv * dv) * (1.0f / 64.0f);
    os[r * 65 + lane] = g1[lane] * dv * rsqrtf(var + 1e-6f) + b1l[lane];
  }
  __syncthreads();

  // ---- FFN: r0 = relu(os@W1+b1)@W2 + b2 + os, chunked over DFF ----
  float r16[4][4] = {};
  for (int nc = 0; nc < 4; ++nc){
    __syncthreads();               // wsb/hs readers from prev chunk done
    for (int i = tid; i < 4096; i += 256)
      wsb[i] = W1[(i >> 6) * DFF + nc * 64 + (i & 63)];
    __syncthreads();
    float f[4][4] = {};
    for (int k = 0; k < 64; ++k){
      float a[4];
#pragma unroll
      for (int i = 0; i < 4; ++i) a[i] = os[(tr * 4 + i) * 65 + k];
      float4 b4 = *(const float4*)&wsb[k * 64 + tc * 4];
#pragma unroll
      for (int i = 0; i < 4; ++i){
        f[i][0] += a[i] * b4.x; f[i][1] += a[i] * b4.y;
        f[i][2] += a[i] * b4.z; f[i][3] += a[i] * b4.w;
      }
    }
    float4 bb = *(const float4*)&b1[nc * 64 + tc * 4];
#pragma unroll
    for (int i = 0; i < 4; ++i){
      hs[(tr * 4 + i) * 65 + tc * 4 + 0] = fmaxf(f[i][0] + bb.x, 0.0f);
      hs[(tr * 4 + i) * 65 + tc * 4 + 1] = fmaxf(f[i][1] + bb.y, 0.0f);
      hs[(tr * 4 + i) * 65 + tc * 4 + 2] = fmaxf(f[i][2] + bb.z, 0.0f);
      hs[(tr * 4 + i) * 65 + tc * 4 + 3] = fmaxf(f[i][3] + bb.w, 0.0f);
    }
    __syncthreads();               // A-chunk visible; wsb readers done
    for (int i = tid; i < 4096; i += 256) wsb[i] = W2[nc * 4096 + i];
    __syncthreads();
    for (int k = 0; k < 64; ++k){
      float a[4];
#pragma unroll
      for (int i = 0; i < 4; ++i) a[i] = hs[(tr * 4 + i) * 65 + k];
      float4 b4 = *(const float4*)&wsb[k * 64 + tc * 4];
#pragma unroll
      for (int i = 0; i < 4; ++i){
        r16[i][0] += a[i] * b4.x; r16[i][1] += a[i] * b4.y;
        r16[i][2] += a[i] * b4.z; r16[i][3] += a[i] * b4.w;
      }
    }
  }
  float4 b24 = *(const float4*)&b2[tc * 4];
#pragma unroll
  for (int i = 0; i < 4; ++i){
    r16[i][0] += b24.x + os[(tr * 4 + i) * 65 + tc * 4 + 0];
    r16[i][1] += b24.y + os[(tr * 4 + i) * 65 + tc * 4 + 1];
    r16[i][2] += b24.z + os[(tr * 4 + i) * 65 + tc * 4 + 2];
    r16[i][3] += b24.w + os[(tr * 4 + i) * 65 + tc * 4 + 3];
  }
  __syncthreads();                 // hs(A last chunk) readers done
#pragma unroll
  for (int i = 0; i < 4; ++i){
    hs[(tr * 4 + i) * 65 + tc * 4 + 0] = r16[i][0];
    hs[(tr * 4 + i) * 65 + tc * 4 + 1] = r16[i][1];
    hs[(tr * 4 + i) * 65 + tc * 4 + 2] = r16[i][2];
    hs[(tr * 4 + i) * 65 + tc * 4 + 3] = r16[i][3];
  }
  __syncthreads();

  // ---- LN2 -> R, pred, pred_resampl ----
  float wf = Wf[lane];
  float bfv = bf[0];
  for (int r = wid; r < 64; r += 4){
    float h = hs[r * 65 + lane];
    float mu = wred_sum(h) * (1.0f / 64.0f);
    float dv = h - mu;
    float var = wred_sum(dv * dv) * (1.0f / 64.0f);
    float rv = g2[lane] * dv * rsqrtf(var + 1e-6f) + b2l[lane];
    Rout[(row0 + r) * 64 + lane] = rv;
    float ps = wred_sum(rv * wf);
    if (lane == 0){
      pred[row0 + r]  = ps + bfv;
      predr[row0 + r] = ps + bfv;
    }
  }
}

extern "C" void kernel_launch(void* const* d_in, const int* in_sizes, int n_in,
                              void* d_out, int out_size, void* d_ws, size_t ws_size,
                              hipStream_t stream){
  const float* inputs = (const float*)d_in[0];
  // d_in[1] = targets (unused by the reference outputs)
  const float* Wp  = (const float*)d_in[2];
  const float* bpj = (const float*)d_in[3];
  const float* Wq  = (const float*)d_in[4];  const float* bq = (const float*)d_in[5];
  const float* Wk  = (const float*)d_in[6];  const float* bk = (const float*)d_in[7];
  const float* Wv  = (const float*)d_in[8];  const float* bv = (const float*)d_in[9];
  const float* Wo  = (const float*)d_in[10]; const float* bo = (const float*)d_in[11];
  const float* g1  = (const float*)d_in[12]; const float* b1l = (const float*)d_in[13];
  const float* W1  = (const float*)d_in[14]; const float* b1 = (const float*)d_in[15];
  const float* W2  = (const float*)d_in[16]; const float* b2 = (const float*)d_in[17];
  const float* g2  = (const float*)d_in[18]; const float* b2l = (const float*)d_in[19];
  const float* Wf  = (const float*)d_in[20]; const float* bf = (const float*)d_in[21];

  float* out = (float*)d_out;
  float* ws  = (float*)d_ws;
  float* x = ws;                 // 819200
  float* Q = ws + 819200;        // 819200
  float* Z = ws + 1638400;       // 819200

  float* pred  = out + OFF_PRED;
  float* predr = out + OFF_PREDR;
  float* Kc    = out + OFF_K;
  float* Vc    = out + OFF_V;
  float* Rr    = out + OFF_R;
  float* attn  = out + OFF_ATTN;

  k_proj<<<NROW * DD / 256, 256, 0, stream>>>(inputs, Wp, bpj, x);
  k_qkv<<<NROW / 64, 256, 0, stream>>>(x, Wq, bq, Wk, bk, Wv, bv, Q, Kc, Vc);
  k_attn_logits<<<NBP, 256, 0, stream>>>(Q, Kc, attn);
  k_attn_z<<<NBP, 256, 0, stream>>>(attn, Vc, Z);
  k_post<<<NROW / 64, 256, 0, stream>>>(Z, x, Wo, bo, g1, b1l, W1, b1,
                                        W2, b2, g2, b2l, Wf, bf, Rr, pred, predr);
}

// Round 2
// 222.244 us; speedup vs baseline: 1.2919x; 1.2919x over previous
//
#include <hip/hip_runtime.h>
#include <math.h>

#define BB 8
#define PP 10
#define SS 160
#define FXD 11
#define DD 64
#define DFF 256
#define NROW (BB*PP*SS)   /* 12800 */
#define NBP  (BB*PP)      /* 80 */

// d_out layout (floats): pred | pred_resampl | K | V | R | attn
#define OFF_PRED  0
#define OFF_PREDR 12800
#define OFF_K     25600
#define OFF_V     844800
#define OFF_R     1664000
#define OFF_ATTN  2483200

__device__ __forceinline__ float wred_sum(float v){
#pragma unroll
  for (int m = 32; m >= 1; m >>= 1) v += __shfl_xor(v, m, 64);
  return v;
}
__device__ __forceinline__ float wred_max(float v){
#pragma unroll
  for (int m = 32; m >= 1; m >>= 1) v = fmaxf(v, __shfl_xor(v, m, 64));
  return v;
}

// ---------------------------------------------------------------------------
// x = (inp @ Wp + bp) * 8 ; Q/K/V = x @ W{q,k,v} + b.  32-row tiles, 400 blocks.
// Weights read from global (16KB each, L1-resident); x staged in LDS.
// ---------------------------------------------------------------------------
__global__ __launch_bounds__(256) void k_xqkv(const float* __restrict__ inp,
    const float* __restrict__ Wp, const float* __restrict__ bpj,
    const float* __restrict__ Wq, const float* __restrict__ bq,
    const float* __restrict__ Wk, const float* __restrict__ bk,
    const float* __restrict__ Wv, const float* __restrict__ bv,
    float* __restrict__ x, float* __restrict__ Q,
    float* __restrict__ Kc, float* __restrict__ Vc){
  __shared__ __align__(16) float ins[32*12];
  __shared__ __align__(16) float xs[32*68];
  int tid = threadIdx.x;
  int row0 = blockIdx.x * 32;
  for (int i = tid; i < 32*FXD; i += 256){
    int r = i / FXD; int f = i - r*FXD;
    ins[r*12 + f] = inp[row0*FXD + i];
  }
  __syncthreads();
  int tc = tid & 15, tr = tid >> 4;       // 16 col-groups x 16 row-groups(2 rows)
  int r0 = tr*2, r1 = r0+1;
  {
    float a0[4] = {}, a1[4] = {};
#pragma unroll
    for (int f = 0; f < FXD; ++f){
      float v0 = ins[r0*12+f], v1 = ins[r1*12+f];
      float4 b4 = *(const float4*)&Wp[f*64 + tc*4];
      a0[0]+=v0*b4.x; a0[1]+=v0*b4.y; a0[2]+=v0*b4.z; a0[3]+=v0*b4.w;
      a1[0]+=v1*b4.x; a1[1]+=v1*b4.y; a1[2]+=v1*b4.z; a1[3]+=v1*b4.w;
    }
    float4 bp4 = *(const float4*)&bpj[tc*4];
    float4 x0 = make_float4((a0[0]+bp4.x)*8.f,(a0[1]+bp4.y)*8.f,(a0[2]+bp4.z)*8.f,(a0[3]+bp4.w)*8.f);
    float4 x1 = make_float4((a1[0]+bp4.x)*8.f,(a1[1]+bp4.y)*8.f,(a1[2]+bp4.z)*8.f,(a1[3]+bp4.w)*8.f);
    *(float4*)&xs[r0*68 + tc*4] = x0;
    *(float4*)&xs[r1*68 + tc*4] = x1;
    *(float4*)&x[(row0+r0)*64 + tc*4] = x0;
    *(float4*)&x[(row0+r1)*64 + tc*4] = x1;
  }
  __syncthreads();
  const float* Wt[3] = {Wq, Wk, Wv};
  const float* bt[3] = {bq, bk, bv};
  float* Ot[3] = {Q, Kc, Vc};
#pragma unroll
  for (int w = 0; w < 3; ++w){
    const float* W = Wt[w];
    float c0[4] = {}, c1[4] = {};
    for (int k = 0; k < 64; ++k){
      float v0 = xs[r0*68+k], v1 = xs[r1*68+k];
      float4 b4 = *(const float4*)&W[k*64 + tc*4];
      c0[0]+=v0*b4.x; c0[1]+=v0*b4.y; c0[2]+=v0*b4.z; c0[3]+=v0*b4.w;
      c1[0]+=v1*b4.x; c1[1]+=v1*b4.y; c1[2]+=v1*b4.z; c1[3]+=v1*b4.w;
    }
    float4 bb = *(const float4*)&bt[w][tc*4];
    *(float4*)&Ot[w][(row0+r0)*64+tc*4] = make_float4(c0[0]+bb.x,c0[1]+bb.y,c0[2]+bb.z,c0[3]+bb.w);
    *(float4*)&Ot[w][(row0+r1)*64+tc*4] = make_float4(c1[0]+bb.x,c1[1]+bb.y,c1[2]+bb.z,c1[3]+bb.w);
  }
}

// ---------------------------------------------------------------------------
// Fused attention: logits+softmax (-> attn out, ps LDS), Z = P@V, zo = Z@Wo+bo+x,
// LN1 -> out.  Grid (80 bp, 5 t-chunks of 32) = 400 blocks.
// ---------------------------------------------------------------------------
__global__ __launch_bounds__(256) void k_attn(const float* __restrict__ Q,
    const float* __restrict__ Kout, const float* __restrict__ Vout,
    const float* __restrict__ Wo, const float* __restrict__ bo,
    const float* __restrict__ g1, const float* __restrict__ b1l,
    const float* __restrict__ x,
    float* __restrict__ attn, float* __restrict__ out){
  __shared__ __align__(16) float smem[17728];
  float* ks  = smem;            // 160*65 = 10400 (phase A)
  float* qs  = smem + 10400;    // 32*68  = 2176
  float* ps  = smem + 12576;    // 32*161 = 5152
  float* Zs  = smem;            // 32*68 (reuse of ks region, phases B/C)
  float* zos = smem + 2176;     // 32*68

  int tid = threadIdx.x;
  int bp = blockIdx.x, c = blockIdx.y;
  int t0g = c*32, tend = t0g + 32;
  const float* Kb = Kout + bp*(SS*DD);
  const float* Vb = Vout + bp*(SS*DD);
  const float* Qb = Q + bp*(SS*DD);
  float* Ab = attn + bp*(SS*SS);

  for (int i = tid; i < tend*64; i += 256){   // stage K[0..tend)
    int r = i >> 6, e = i & 63;
    ks[r*65 + e] = Kb[i];
  }
  for (int i = tid; i < 32*16; i += 256){     // stage Q chunk rows
    int r = i >> 4, c4 = (i & 15)*4;
    *(float4*)&qs[r*68 + c4] = *(const float4*)&Qb[(t0g + r)*64 + c4];
  }
  __syncthreads();

  int lane = tid & 63, wid = tid >> 6;
  int s0 = lane, s1 = lane + 64, s2 = lane + 128;
  int a0 = s0*65, a1 = s1*65, a2 = (s2 < SS ? s2 : 0)*65;

  // phase A: logits + softmax; rows beyond t masked to exact 0
  for (int g = wid; g < 8; g += 4){
    int lt0 = g*4;
    float acc[4][3] = {};
    for (int e = 0; e < 64; ++e){
      float k0 = ks[a0+e], k1 = ks[a1+e], k2 = ks[a2+e];
      float q0 = qs[(lt0+0)*68+e], q1 = qs[(lt0+1)*68+e];
      float q2 = qs[(lt0+2)*68+e], q3 = qs[(lt0+3)*68+e];
      acc[0][0]+=q0*k0; acc[0][1]+=q0*k1; acc[0][2]+=q0*k2;
      acc[1][0]+=q1*k0; acc[1][1]+=q1*k1; acc[1][2]+=q1*k2;
      acc[2][0]+=q2*k0; acc[2][1]+=q2*k1; acc[2][2]+=q2*k2;
      acc[3][0]+=q3*k0; acc[3][1]+=q3*k1; acc[3][2]+=q3*k2;
    }
#pragma unroll
    for (int tt = 0; tt < 4; ++tt){
      int lt = lt0 + tt;
      int t = t0g + lt;
      bool v0 = (s0 <= t), v1 = (s1 <= t), v2 = (s2 <= t) && (s2 < SS);
      float l0 = v0 ? acc[tt][0]*0.125f : -INFINITY;
      float l1 = v1 ? acc[tt][1]*0.125f : -INFINITY;
      float l2 = v2 ? acc[tt][2]*0.125f : -INFINITY;
      float m = wred_max(fmaxf(l0, fmaxf(l1, l2)));
      float e0 = v0 ? __expf(l0-m) : 0.f;
      float e1 = v1 ? __expf(l1-m) : 0.f;
      float e2 = v2 ? __expf(l2-m) : 0.f;
      float inv = 1.0f / wred_sum(e0+e1+e2);
      float p0 = e0*inv, p1 = e1*inv, p2 = e2*inv;
      float* Arow = &Ab[t*SS];
      Arow[s0] = p0; ps[lt*161 + s0] = p0;
      Arow[s1] = p1; ps[lt*161 + s1] = p1;
      if (s2 < SS){ Arow[s2] = p2; ps[lt*161 + s2] = p2; }
    }
  }
  __syncthreads();

  // phase B: Z (32x64) = P @ V (V from global, L1-resident)
  int tc = tid & 15, tr = tid >> 4;
  int rr0 = tr*2, rr1 = rr0 + 1;
  {
    float z0[4] = {}, z1[4] = {};
    for (int s = 0; s < tend; ++s){
      float p0 = ps[rr0*161 + s], p1 = ps[rr1*161 + s];
      float4 v4 = *(const float4*)&Vb[s*64 + tc*4];
      z0[0]+=p0*v4.x; z0[1]+=p0*v4.y; z0[2]+=p0*v4.z; z0[3]+=p0*v4.w;
      z1[0]+=p1*v4.x; z1[1]+=p1*v4.y; z1[2]+=p1*v4.z; z1[3]+=p1*v4.w;
    }
    *(float4*)&Zs[rr0*68 + tc*4] = make_float4(z0[0],z0[1],z0[2],z0[3]);
    *(float4*)&Zs[rr1*68 + tc*4] = make_float4(z1[0],z1[1],z1[2],z1[3]);
  }
  __syncthreads();

  // phase C: zo = Z@Wo + bo + x  -> zos
  {
    float c0[4] = {}, c1[4] = {};
    for (int k = 0; k < 64; ++k){
      float z0 = Zs[rr0*68+k], z1 = Zs[rr1*68+k];
      float4 b4 = *(const float4*)&Wo[k*64 + tc*4];
      c0[0]+=z0*b4.x; c0[1]+=z0*b4.y; c0[2]+=z0*b4.z; c0[3]+=z0*b4.w;
      c1[0]+=z1*b4.x; c1[1]+=z1*b4.y; c1[2]+=z1*b4.z; c1[3]+=z1*b4.w;
    }
    float4 bo4 = *(const float4*)&bo[tc*4];
    float4 xr0 = *(const float4*)&x[(bp*SS + t0g + rr0)*64 + tc*4];
    float4 xr1 = *(const float4*)&x[(bp*SS + t0g + rr1)*64 + tc*4];
    *(float4*)&zos[rr0*68 + tc*4] = make_float4(c0[0]+bo4.x+xr0.x, c0[1]+bo4.y+xr0.y,
                                                c0[2]+bo4.z+xr0.z, c0[3]+bo4.w+xr0.w);
    *(float4*)&zos[rr1*68 + tc*4] = make_float4(c1[0]+bo4.x+xr1.x, c1[1]+bo4.y+xr1.y,
                                                c1[2]+bo4.z+xr1.z, c1[3]+bo4.w+xr1.w);
  }
  __syncthreads();

  // LN1 -> out
  for (int r = wid; r < 32; r += 4){
    float h = zos[r*68 + lane];
    float mu = wred_sum(h) * (1.f/64.f);
    float dv = h - mu;
    float var = wred_sum(dv*dv) * (1.f/64.f);
    out[(bp*SS + t0g + r)*64 + lane] = g1[lane]*dv*rsqrtf(var + 1e-6f) + b1l[lane];
  }
}

// ---------------------------------------------------------------------------
// FFN fused: a = relu(out@W1+b1) (LDS only), r0 = a@W2+b2+out (split-K x4),
// LN2 -> R, pred = R@Wf+bf.  16-row tiles, 800 blocks, ~37KB LDS.
// ---------------------------------------------------------------------------
__global__ __launch_bounds__(256) void k_ffn(const float* __restrict__ out,
    const float* __restrict__ W1, const float* __restrict__ b1,
    const float* __restrict__ W2, const float* __restrict__ b2,
    const float* __restrict__ g2, const float* __restrict__ b2l,
    const float* __restrict__ Wf, const float* __restrict__ bf,
    float* __restrict__ R, float* __restrict__ pred, float* __restrict__ predr){
  __shared__ __align__(16) float os[16*68];
  __shared__ __align__(16) float as[16*260];
  __shared__ __align__(16) float red[4096];
  int tid = threadIdx.x;
  int row0 = blockIdx.x * 16;
  for (int i = tid; i < 16*16; i += 256){
    int r = i >> 4, c4 = (i & 15)*4;
    *(float4*)&os[r*68 + c4] = *(const float4*)&out[(row0+r)*64 + c4];
  }
  __syncthreads();
  // FFN1: 16x256, K=64.  tc over 256 cols (coalesced W1), tr = wave (a-broadcast)
  {
    int tc = tid & 63, tr = tid >> 6;
    float acc[4][4] = {};
    for (int k = 0; k < 64; ++k){
      float4 b4 = *(const float4*)&W1[k*256 + tc*4];
      float a0 = os[(tr*4+0)*68+k], a1 = os[(tr*4+1)*68+k];
      float a2 = os[(tr*4+2)*68+k], a3 = os[(tr*4+3)*68+k];
      acc[0][0]+=a0*b4.x; acc[0][1]+=a0*b4.y; acc[0][2]+=a0*b4.z; acc[0][3]+=a0*b4.w;
      acc[1][0]+=a1*b4.x; acc[1][1]+=a1*b4.y; acc[1][2]+=a1*b4.z; acc[1][3]+=a1*b4.w;
      acc[2][0]+=a2*b4.x; acc[2][1]+=a2*b4.y; acc[2][2]+=a2*b4.z; acc[2][3]+=a2*b4.w;
      acc[3][0]+=a3*b4.x; acc[3][1]+=a3*b4.y; acc[3][2]+=a3*b4.z; acc[3][3]+=a3*b4.w;
    }
    float4 bb = *(const float4*)&b1[tc*4];
#pragma unroll
    for (int i = 0; i < 4; ++i){
      *(float4*)&as[(tr*4+i)*260 + tc*4] = make_float4(
        fmaxf(acc[i][0]+bb.x,0.f), fmaxf(acc[i][1]+bb.y,0.f),
        fmaxf(acc[i][2]+bb.z,0.f), fmaxf(acc[i][3]+bb.w,0.f));
    }
  }
  __syncthreads();
  // FFN2: 16x64, K=256 split into 4 k-partitions (one per wave)
  int kp = tid >> 6, lane = tid & 63;
  int tc2 = lane & 15, tr2 = lane >> 4;
  {
    float acc[4][4] = {};
    int kbase = kp*64;
    for (int kk = 0; kk < 64; ++kk){
      int k = kbase + kk;
      float4 b4 = *(const float4*)&W2[k*64 + tc2*4];
      float a0 = as[(tr2*4+0)*260+k], a1 = as[(tr2*4+1)*260+k];
      float a2 = as[(tr2*4+2)*260+k], a3 = as[(tr2*4+3)*260+k];
      acc[0][0]+=a0*b4.x; acc[0][1]+=a0*b4.y; acc[0][2]+=a0*b4.z; acc[0][3]+=a0*b4.w;
      acc[1][0]+=a1*b4.x; acc[1][1]+=a1*b4.y; acc[1][2]+=a1*b4.z; acc[1][3]+=a1*b4.w;
      acc[2][0]+=a2*b4.x; acc[2][1]+=a2*b4.y; acc[2][2]+=a2*b4.z; acc[2][3]+=a2*b4.w;
      acc[3][0]+=a3*b4.x; acc[3][1]+=a3*b4.y; acc[3][2]+=a3*b4.z; acc[3][3]+=a3*b4.w;
    }
#pragma unroll
    for (int i = 0; i < 4; ++i)
      *(float4*)&red[kp*1024 + (tr2*4+i)*64 + tc2*4] =
        make_float4(acc[i][0], acc[i][1], acc[i][2], acc[i][3]);
  }
  __syncthreads();
  // reduce partials + residual + LN2 + pred
  float wfv = Wf[lane];
  float bfv = bf[0];
  int w = tid >> 6;
#pragma unroll
  for (int j = 0; j < 4; ++j){
    int r = w*4 + j;
    float h = red[r*64+lane] + red[1024 + r*64+lane]
            + red[2048 + r*64+lane] + red[3072 + r*64+lane]
            + b2[lane] + os[r*68 + lane];
    float mu = wred_sum(h) * (1.f/64.f);
    float dv = h - mu;
    float var = wred_sum(dv*dv) * (1.f/64.f);
    float rv = g2[lane]*dv*rsqrtf(var + 1e-6f) + b2l[lane];
    R[(row0+r)*64 + lane] = rv;
    float pw = wred_sum(rv * wfv);
    if (lane == 0){ pred[row0+r] = pw + bfv; predr[row0+r] = pw + bfv; }
  }
}

extern "C" void kernel_launch(void* const* d_in, const int* in_sizes, int n_in,
                              void* d_out, int out_size, void* d_ws, size_t ws_size,
                              hipStream_t stream){
  const float* inputs = (const float*)d_in[0];
  const float* Wp  = (const float*)d_in[2];
  const float* bpj = (const float*)d_in[3];
  const float* Wq  = (const float*)d_in[4];  const float* bq  = (const float*)d_in[5];
  const float* Wk  = (const float*)d_in[6];  const float* bk  = (const float*)d_in[7];
  const float* Wv  = (const float*)d_in[8];  const float* bv  = (const float*)d_in[9];
  const float* Wo  = (const float*)d_in[10]; const float* bo  = (const float*)d_in[11];
  const float* g1  = (const float*)d_in[12]; const float* b1l = (const float*)d_in[13];
  const float* W1  = (const float*)d_in[14]; const float* b1  = (const float*)d_in[15];
  const float* W2  = (const float*)d_in[16]; const float* b2  = (const float*)d_in[17];
  const float* g2  = (const float*)d_in[18]; const float* b2l = (const float*)d_in[19];
  const float* Wf  = (const float*)d_in[20]; const float* bf  = (const float*)d_in[21];

  float* outp = (float*)d_out;
  float* ws   = (float*)d_ws;
  float* x    = ws;                 // 819200 floats
  float* Qw   = ws + 819200;        // 819200
  float* outb = ws + 1638400;       // 819200 (LN1 output)

  float* pred  = outp + OFF_PRED;
  float* predr = outp + OFF_PREDR;
  float* Kc    = outp + OFF_K;
  float* Vc    = outp + OFF_V;
  float* Rr    = outp + OFF_R;
  float* attn  = outp + OFF_ATTN;

  k_xqkv<<<NROW/32, 256, 0, stream>>>(inputs, Wp, bpj, Wq, bq, Wk, bk, Wv, bv,
                                      x, Qw, Kc, Vc);
  k_attn<<<dim3(NBP, 5), 256, 0, stream>>>(Qw, Kc, Vc, Wo, bo, g1, b1l, x,
                                           attn, outb);
  k_ffn<<<NROW/16, 256, 0, stream>>>(outb, W1, b1, W2, b2, g2, b2l, Wf, bf,
                                     Rr, pred, predr);
}

// Round 4
// 175.856 us; speedup vs baseline: 1.6326x; 1.2638x over previous
//
#include <hip/hip_runtime.h>
#include <math.h>

#define BB 8
#define PP 10
#define SS 160
#define FXD 11
#define DD 64
#define DFF 256
#define NROW (BB*PP*SS)   /* 12800 */
#define NBP  (BB*PP)      /* 80 */

// d_out layout (floats): pred | pred_resampl | K | V | R | attn
#define OFF_PRED  0
#define OFF_PREDR 12800
#define OFF_K     25600
#define OFF_V     844800
#define OFF_R     1664000
#define OFF_ATTN  2483200

__device__ __forceinline__ void fma4(float4& acc, float s, const float4& b){
  acc.x += s*b.x; acc.y += s*b.y; acc.z += s*b.z; acc.w += s*b.w;
}

__device__ __forceinline__ float wred_sum(float v){
#pragma unroll
  for (int m = 32; m >= 1; m >>= 1) v += __shfl_xor(v, m, 64);
  return v;
}
__device__ __forceinline__ float wred_max(float v){
#pragma unroll
  for (int m = 32; m >= 1; m >>= 1) v = fmaxf(v, __shfl_xor(v, m, 64));
  return v;
}

// ---------------------------------------------------------------------------
// Fused proj + QKV. 16-row tiles, 800 blocks. Weights staged in LDS; all
// inner-loop reads are LDS b128 / broadcast.
// ---------------------------------------------------------------------------
__global__ __launch_bounds__(256) void k_xqkv(const float* __restrict__ inp,
    const float* __restrict__ Wp, const float* __restrict__ bpj,
    const float* __restrict__ Wq, const float* __restrict__ bq,
    const float* __restrict__ Wk, const float* __restrict__ bk,
    const float* __restrict__ Wv, const float* __restrict__ bv,
    float* __restrict__ x, float* __restrict__ Q,
    float* __restrict__ Kc, float* __restrict__ Vc){
  __shared__ __align__(16) float ins[16*12];
  __shared__ __align__(16) float xs[16*68];
  __shared__ __align__(16) float wsb[64*64];
  int tid = threadIdx.x;
  int row0 = blockIdx.x * 16;
  for (int i = tid; i < 16*FXD; i += 256){
    int r = i / FXD, f = i - r*FXD;
    ins[r*12 + f] = inp[row0*FXD + i];
  }
  __syncthreads();
  int tc = tid & 15, tr = tid >> 4;   // tr = row (0..15), tc = d4 (0..15)
  // x = (inp @ Wp + bp) * 8
  {
    float4 a = make_float4(0.f,0.f,0.f,0.f);
#pragma unroll
    for (int f = 0; f < FXD; ++f){
      float v = ins[tr*12 + f];
      float4 w4 = *(const float4*)&Wp[f*64 + tc*4];
      fma4(a, v, w4);
    }
    float4 bp4 = *(const float4*)&bpj[tc*4];
    float4 xv = make_float4((a.x+bp4.x)*8.f, (a.y+bp4.y)*8.f,
                            (a.z+bp4.z)*8.f, (a.w+bp4.w)*8.f);
    *(float4*)&xs[tr*68 + tc*4] = xv;
    *(float4*)&x[(row0+tr)*64 + tc*4] = xv;
  }
  const float* Wt[3] = {Wq, Wk, Wv};
  const float* bt[3] = {bq, bk, bv};
  float* Ot[3] = {Q, Kc, Vc};
  for (int w = 0; w < 3; ++w){
    __syncthreads();                       // xs ready (w=0); wsb readers done
    {
      const float4* Wsrc = (const float4*)Wt[w];
      float4* Wdst = (float4*)wsb;
#pragma unroll
      for (int i = 0; i < 4; ++i) Wdst[tid + i*256] = Wsrc[tid + i*256];
    }
    __syncthreads();
    float4 acc = make_float4(0.f,0.f,0.f,0.f);
#pragma unroll 4
    for (int k4 = 0; k4 < 16; ++k4){
      float4 xv = *(const float4*)&xs[tr*68 + k4*4];
      float4 w0 = *(const float4*)&wsb[(k4*4+0)*64 + tc*4];
      float4 w1 = *(const float4*)&wsb[(k4*4+1)*64 + tc*4];
      float4 w2 = *(const float4*)&wsb[(k4*4+2)*64 + tc*4];
      float4 w3 = *(const float4*)&wsb[(k4*4+3)*64 + tc*4];
      fma4(acc, xv.x, w0); fma4(acc, xv.y, w1);
      fma4(acc, xv.z, w2); fma4(acc, xv.w, w3);
    }
    float4 bb = *(const float4*)&bt[w][tc*4];
    *(float4*)&Ot[w][(row0+tr)*64 + tc*4] =
      make_float4(acc.x+bb.x, acc.y+bb.y, acc.z+bb.z, acc.w+bb.w);
  }
}

// ---------------------------------------------------------------------------
// Fused attention: logits+softmax -> attn/ps, Z = P@V, zo = Z@Wo+bo+x, LN1.
// Grid (80 bp, 10 chunks of 16 t) = 800 blocks. ~57KB LDS -> 2 blocks/CU.
// ---------------------------------------------------------------------------
__global__ __launch_bounds__(256) void k_attn(const float* __restrict__ Q,
    const float* __restrict__ Kout, const float* __restrict__ Vout,
    const float* __restrict__ Wo, const float* __restrict__ bo,
    const float* __restrict__ g1, const float* __restrict__ b1l,
    const float* __restrict__ x,
    float* __restrict__ attn, float* __restrict__ out){
  __shared__ __align__(16) float ks[160*68];   // K staged (stride 68 for b128)
  __shared__ __align__(16) float qs[16*68];
  __shared__ __align__(16) float ps[16*164];
  float* Zs  = ks;            // reuse (rows 0..15)
  float* zos = ks + 16*68;    // reuse (rows 16..31)

  int tid = threadIdx.x;
  int bp = blockIdx.x, c = blockIdx.y;
  int t0g = c*16, tend = t0g + 16;
  int ng = (tend + 63) >> 6;           // block-uniform group count
  const float* Kb = Kout + bp*(SS*DD);
  const float* Vb = Vout + bp*(SS*DD);
  const float* Qb = Q + bp*(SS*DD);
  float* Ab = attn + bp*(SS*SS);

  for (int i = tid; i < tend*16; i += 256){
    int r = i >> 4, e4 = (i & 15)*4;
    *(float4*)&ks[r*68 + e4] = *(const float4*)&Kb[r*64 + e4];
  }
  {
    int r = tid >> 4, e4 = (tid & 15)*4;
    *(float4*)&qs[r*68 + e4] = *(const float4*)&Qb[(t0g + r)*64 + e4];
  }
  __syncthreads();

  int lane = tid & 63, wid = tid >> 6;
  int s0 = lane, s1 = lane + 64, s2 = lane + 128;
  int a0 = s0*68, a1 = s1*68, a2 = (s2 < SS ? s2 : 0)*68;

  // phase A: logits + softmax. Each wave: 4 rows.
  {
    float acc[4][3] = {};
#pragma unroll 4
    for (int e4 = 0; e4 < 16; ++e4){
      float4 k0 = *(const float4*)&ks[a0 + e4*4];
      float4 k1 = k0, k2 = k0;
      if (ng > 1) k1 = *(const float4*)&ks[a1 + e4*4];
      if (ng > 2) k2 = *(const float4*)&ks[a2 + e4*4];
#pragma unroll
      for (int tt = 0; tt < 4; ++tt){
        float4 q4 = *(const float4*)&qs[(wid*4+tt)*68 + e4*4];
        acc[tt][0] += q4.x*k0.x + q4.y*k0.y + q4.z*k0.z + q4.w*k0.w;
        if (ng > 1) acc[tt][1] += q4.x*k1.x + q4.y*k1.y + q4.z*k1.z + q4.w*k1.w;
        if (ng > 2) acc[tt][2] += q4.x*k2.x + q4.y*k2.y + q4.z*k2.z + q4.w*k2.w;
      }
    }
#pragma unroll
    for (int tt = 0; tt < 4; ++tt){
      int lt = wid*4 + tt;
      int t = t0g + lt;
      bool v0 = (s0 <= t), v1 = (s1 <= t), v2 = (s2 <= t) && (s2 < SS);
      float l0 = v0 ? acc[tt][0]*0.125f : -INFINITY;
      float l1 = v1 ? acc[tt][1]*0.125f : -INFINITY;
      float l2 = v2 ? acc[tt][2]*0.125f : -INFINITY;
      float m = wred_max(fmaxf(l0, fmaxf(l1, l2)));
      float e0 = v0 ? __expf(l0-m) : 0.f;
      float e1 = v1 ? __expf(l1-m) : 0.f;
      float e2 = v2 ? __expf(l2-m) : 0.f;
      float inv = 1.0f / wred_sum(e0+e1+e2);
      float p0 = e0*inv, p1 = e1*inv, p2 = e2*inv;
      float* Arow = &Ab[t*SS];
      Arow[s0] = p0; ps[lt*164 + s0] = p0;
      Arow[s1] = p1; ps[lt*164 + s1] = p1;
      if (s2 < SS){ Arow[s2] = p2; ps[lt*164 + s2] = p2; }
    }
  }
  __syncthreads();

  // phase B: Z(16x64) = P @ V (V from global, coalesced, unrolled)
  int tc = tid & 15, tr = tid >> 4;
  {
    float4 z = make_float4(0.f,0.f,0.f,0.f);
    int pb = tr*164;
#pragma unroll 4
    for (int s = 0; s < tend; ++s){
      float p = ps[pb + s];
      float4 v4 = *(const float4*)&Vb[s*64 + tc*4];
      fma4(z, p, v4);
    }
    *(float4*)&Zs[tr*68 + tc*4] = z;
  }
  __syncthreads();

  // phase C: zo = Z@Wo + bo + x
  {
    float4 acc = make_float4(0.f,0.f,0.f,0.f);
#pragma unroll 4
    for (int k4 = 0; k4 < 16; ++k4){
      float4 z4 = *(const float4*)&Zs[tr*68 + k4*4];
      float4 w0 = *(const float4*)&Wo[(k4*4+0)*64 + tc*4];
      float4 w1 = *(const float4*)&Wo[(k4*4+1)*64 + tc*4];
      float4 w2 = *(const float4*)&Wo[(k4*4+2)*64 + tc*4];
      float4 w3 = *(const float4*)&Wo[(k4*4+3)*64 + tc*4];
      fma4(acc, z4.x, w0); fma4(acc, z4.y, w1);
      fma4(acc, z4.z, w2); fma4(acc, z4.w, w3);
    }
    float4 bo4 = *(const float4*)&bo[tc*4];
    float4 xr  = *(const float4*)&x[(bp*SS + t0g + tr)*64 + tc*4];
    *(float4*)&zos[tr*68 + tc*4] = make_float4(acc.x+bo4.x+xr.x, acc.y+bo4.y+xr.y,
                                               acc.z+bo4.z+xr.z, acc.w+bo4.w+xr.w);
  }
  __syncthreads();

  // LN1 -> out
  for (int r = wid; r < 16; r += 4){
    float h = zos[r*68 + lane];
    float mu = wred_sum(h) * (1.f/64.f);
    float dv = h - mu;
    float var = wred_sum(dv*dv) * (1.f/64.f);
    out[(bp*SS + t0g + r)*64 + lane] = g1[lane]*dv*rsqrtf(var + 1e-6f) + b1l[lane];
  }
}

// ---------------------------------------------------------------------------
// FFN fused: a = relu(out@W1+b1) (LDS only), r0 = a@W2+b2+out (split-K x4),
// LN2 -> R, pred = R@Wf+bf.  16-row tiles, 800 blocks, ~37KB LDS.
// ---------------------------------------------------------------------------
__global__ __launch_bounds__(256) void k_ffn(const float* __restrict__ out,
    const float* __restrict__ W1, const float* __restrict__ b1,
    const float* __restrict__ W2, const float* __restrict__ b2,
    const float* __restrict__ g2, const float* __restrict__ b2l,
    const float* __restrict__ Wf, const float* __restrict__ bf,
    float* __restrict__ R, float* __restrict__ pred, float* __restrict__ predr){
  __shared__ __align__(16) float os[16*68];
  __shared__ __align__(16) float as[16*260];
  __shared__ __align__(16) float red[4096];
  int tid = threadIdx.x;
  int row0 = blockIdx.x * 16;
  {
    int r = tid >> 4, c4 = (tid & 15)*4;
    *(float4*)&os[r*68 + c4] = *(const float4*)&out[(row0+r)*64 + c4];
  }
  __syncthreads();
  // FFN1: 16x256, K=64. tc over 64 col-groups (coalesced W1), tr = wave (4 rows)
  {
    int tc = tid & 63, tr = tid >> 6;
    float4 acc[4];
#pragma unroll
    for (int i = 0; i < 4; ++i) acc[i] = make_float4(0.f,0.f,0.f,0.f);
#pragma unroll 2
    for (int k4 = 0; k4 < 16; ++k4){
      float4 a0 = *(const float4*)&os[(tr*4+0)*68 + k4*4];
      float4 a1 = *(const float4*)&os[(tr*4+1)*68 + k4*4];
      float4 a2 = *(const float4*)&os[(tr*4+2)*68 + k4*4];
      float4 a3 = *(const float4*)&os[(tr*4+3)*68 + k4*4];
      float4 w0 = *(const float4*)&W1[(k4*4+0)*256 + tc*4];
      float4 w1 = *(const float4*)&W1[(k4*4+1)*256 + tc*4];
      float4 w2 = *(const float4*)&W1[(k4*4+2)*256 + tc*4];
      float4 w3 = *(const float4*)&W1[(k4*4+3)*256 + tc*4];
      fma4(acc[0], a0.x, w0); fma4(acc[0], a0.y, w1); fma4(acc[0], a0.z, w2); fma4(acc[0], a0.w, w3);
      fma4(acc[1], a1.x, w0); fma4(acc[1], a1.y, w1); fma4(acc[1], a1.z, w2); fma4(acc[1], a1.w, w3);
      fma4(acc[2], a2.x, w0); fma4(acc[2], a2.y, w1); fma4(acc[2], a2.z, w2); fma4(acc[2], a2.w, w3);
      fma4(acc[3], a3.x, w0); fma4(acc[3], a3.y, w1); fma4(acc[3], a3.z, w2); fma4(acc[3], a3.w, w3);
    }
    float4 bb = *(const float4*)&b1[tc*4];
#pragma unroll
    for (int i = 0; i < 4; ++i)
      *(float4*)&as[(tr*4+i)*260 + tc*4] = make_float4(
        fmaxf(acc[i].x+bb.x,0.f), fmaxf(acc[i].y+bb.y,0.f),
        fmaxf(acc[i].z+bb.z,0.f), fmaxf(acc[i].w+bb.w,0.f));
  }
  __syncthreads();
  // FFN2: 16x64, K=256 split into 4 k-partitions (one per wave)
  int kp = tid >> 6, lane = tid & 63;
  int tc2 = lane & 15, tr2 = lane >> 4;
  {
    float4 acc[4];
#pragma unroll
    for (int i = 0; i < 4; ++i) acc[i] = make_float4(0.f,0.f,0.f,0.f);
    int kbase = kp*64;
#pragma unroll 2
    for (int kk4 = 0; kk4 < 16; ++kk4){
      int k = kbase + kk4*4;
      float4 a0 = *(const float4*)&as[(tr2*4+0)*260 + k];
      float4 a1 = *(const float4*)&as[(tr2*4+1)*260 + k];
      float4 a2 = *(const float4*)&as[(tr2*4+2)*260 + k];
      float4 a3 = *(const float4*)&as[(tr2*4+3)*260 + k];
      float4 w0 = *(const float4*)&W2[(k+0)*64 + tc2*4];
      float4 w1 = *(const float4*)&W2[(k+1)*64 + tc2*4];
      float4 w2 = *(const float4*)&W2[(k+2)*64 + tc2*4];
      float4 w3 = *(const float4*)&W2[(k+3)*64 + tc2*4];
      fma4(acc[0], a0.x, w0); fma4(acc[0], a0.y, w1); fma4(acc[0], a0.z, w2); fma4(acc[0], a0.w, w3);
      fma4(acc[1], a1.x, w0); fma4(acc[1], a1.y, w1); fma4(acc[1], a1.z, w2); fma4(acc[1], a1.w, w3);
      fma4(acc[2], a2.x, w0); fma4(acc[2], a2.y, w1); fma4(acc[2], a2.z, w2); fma4(acc[2], a2.w, w3);
      fma4(acc[3], a3.x, w0); fma4(acc[3], a3.y, w1); fma4(acc[3], a3.z, w2); fma4(acc[3], a3.w, w3);
    }
#pragma unroll
    for (int i = 0; i < 4; ++i)
      *(float4*)&red[kp*1024 + (tr2*4+i)*64 + tc2*4] = acc[i];
  }
  __syncthreads();
  // reduce partials + residual + LN2 + pred
  float wfv = Wf[lane];
  float bfv = bf[0];
  int w = tid >> 6;
#pragma unroll
  for (int j = 0; j < 4; ++j){
    int r = w*4 + j;
    float h = red[r*64+lane] + red[1024 + r*64+lane]
            + red[2048 + r*64+lane] + red[3072 + r*64+lane]
            + b2[lane] + os[r*68 + lane];
    float mu = wred_sum(h) * (1.f/64.f);
    float dv = h - mu;
    float var = wred_sum(dv*dv) * (1.f/64.f);
    float rv = g2[lane]*dv*rsqrtf(var + 1e-6f) + b2l[lane];
    R[(row0+r)*64 + lane] = rv;
    float pw = wred_sum(rv * wfv);
    if (lane == 0){ pred[row0+r] = pw + bfv; predr[row0+r] = pw + bfv; }
  }
}

extern "C" void kernel_launch(void* const* d_in, const int* in_sizes, int n_in,
                              void* d_out, int out_size, void* d_ws, size_t ws_size,
                              hipStream_t stream){
  const float* inputs = (const float*)d_in[0];
  const float* Wp  = (const float*)d_in[2];
  const float* bpj = (const float*)d_in[3];
  const float* Wq  = (const float*)d_in[4];  const float* bq  = (const float*)d_in[5];
  const float* Wk  = (const float*)d_in[6];  const float* bk  = (const float*)d_in[7];
  const float* Wv  = (const float*)d_in[8];  const float* bv  = (const float*)d_in[9];
  const float* Wo  = (const float*)d_in[10]; const float* bo  = (const float*)d_in[11];
  const float* g1  = (const float*)d_in[12]; const float* b1l = (const float*)d_in[13];
  const float* W1  = (const float*)d_in[14]; const float* b1  = (const float*)d_in[15];
  const float* W2  = (const float*)d_in[16]; const float* b2  = (const float*)d_in[17];
  const float* g2  = (const float*)d_in[18]; const float* b2l = (const float*)d_in[19];
  const float* Wf  = (const float*)d_in[20]; const float* bf  = (const float*)d_in[21];

  float* outp = (float*)d_out;
  float* ws   = (float*)d_ws;
  float* x    = ws;                 // 819200 floats
  float* Qw   = ws + 819200;        // 819200
  float* outb = ws + 1638400;       // 819200 (LN1 output)

  float* pred  = outp + OFF_PRED;
  float* predr = outp + OFF_PREDR;
  float* Kc    = outp + OFF_K;
  float* Vc    = outp + OFF_V;
  float* Rr    = outp + OFF_R;
  float* attn  = outp + OFF_ATTN;

  k_xqkv<<<NROW/16, 256, 0, stream>>>(inputs, Wp, bpj, Wq, bq, Wk, bk, Wv, bv,
                                      x, Qw, Kc, Vc);
  k_attn<<<dim3(NBP, 10), 256, 0, stream>>>(Qw, Kc, Vc, Wo, bo, g1, b1l, x,
                                            attn, outb);
  k_ffn<<<NROW/16, 256, 0, stream>>>(outb, W1, b1, W2, b2, g2, b2l, Wf, bf,
                                     Rr, pred, predr);
}

// Round 5
// 164.941 us; speedup vs baseline: 1.7407x; 1.0662x over previous
//
#include <hip/hip_runtime.h>
#include <math.h>

#define BB 8
#define PP 10
#define SS 160
#define FXD 11
#define DD 64
#define DFF 256
#define NROW (BB*PP*SS)   /* 12800 */
#define NBP  (BB*PP)      /* 80 */

// d_out layout (floats): pred | pred_resampl | K | V | R | attn
#define OFF_PRED  0
#define OFF_PREDR 12800
#define OFF_K     25600
#define OFF_V     844800
#define OFF_R     1664000
#define OFF_ATTN  2483200

__device__ __forceinline__ void fma4(float4& acc, float s, const float4& b){
  acc.x += s*b.x; acc.y += s*b.y; acc.z += s*b.z; acc.w += s*b.w;
}
__device__ __forceinline__ float wred_sum(float v){
#pragma unroll
  for (int m = 32; m >= 1; m >>= 1) v += __shfl_xor(v, m, 64);
  return v;
}
__device__ __forceinline__ float wred_max(float v){
#pragma unroll
  for (int m = 32; m >= 1; m >>= 1) v = fmaxf(v, __shfl_xor(v, m, 64));
  return v;
}
// bf16 pack/unpack (RTN-even)
__device__ __forceinline__ unsigned f2bf(float f){
  unsigned u = __float_as_uint(f);
  return (u + 0x7fffu + ((u >> 16) & 1u)) >> 16;
}
__device__ __forceinline__ unsigned packbf2(float x, float y){
  return f2bf(x) | (f2bf(y) << 16);
}
__device__ __forceinline__ float bflo(unsigned u){ return __uint_as_float(u << 16); }
__device__ __forceinline__ float bfhi(unsigned u){ return __uint_as_float(u & 0xffff0000u); }

// ---------------------------------------------------------------------------
// Fused proj + QKV. 16-row tiles, 800 blocks. (unchanged from round 4)
// ---------------------------------------------------------------------------
__global__ __launch_bounds__(256) void k_xqkv(const float* __restrict__ inp,
    const float* __restrict__ Wp, const float* __restrict__ bpj,
    const float* __restrict__ Wq, const float* __restrict__ bq,
    const float* __restrict__ Wk, const float* __restrict__ bk,
    const float* __restrict__ Wv, const float* __restrict__ bv,
    float* __restrict__ x, float* __restrict__ Q,
    float* __restrict__ Kc, float* __restrict__ Vc){
  __shared__ __align__(16) float ins[16*12];
  __shared__ __align__(16) float xs[16*68];
  __shared__ __align__(16) float wsb[64*64];
  int tid = threadIdx.x;
  int row0 = blockIdx.x * 16;
  for (int i = tid; i < 16*FXD; i += 256){
    int r = i / FXD, f = i - r*FXD;
    ins[r*12 + f] = inp[row0*FXD + i];
  }
  __syncthreads();
  int tc = tid & 15, tr = tid >> 4;
  {
    float4 a = make_float4(0.f,0.f,0.f,0.f);
#pragma unroll
    for (int f = 0; f < FXD; ++f){
      float v = ins[tr*12 + f];
      float4 w4 = *(const float4*)&Wp[f*64 + tc*4];
      fma4(a, v, w4);
    }
    float4 bp4 = *(const float4*)&bpj[tc*4];
    float4 xv = make_float4((a.x+bp4.x)*8.f, (a.y+bp4.y)*8.f,
                            (a.z+bp4.z)*8.f, (a.w+bp4.w)*8.f);
    *(float4*)&xs[tr*68 + tc*4] = xv;
    *(float4*)&x[(row0+tr)*64 + tc*4] = xv;
  }
  const float* Wt[3] = {Wq, Wk, Wv};
  const float* bt[3] = {bq, bk, bv};
  float* Ot[3] = {Q, Kc, Vc};
  for (int w = 0; w < 3; ++w){
    __syncthreads();
    {
      const float4* Wsrc = (const float4*)Wt[w];
      float4* Wdst = (float4*)wsb;
#pragma unroll
      for (int i = 0; i < 4; ++i) Wdst[tid + i*256] = Wsrc[tid + i*256];
    }
    __syncthreads();
    float4 acc = make_float4(0.f,0.f,0.f,0.f);
#pragma unroll 4
    for (int k4 = 0; k4 < 16; ++k4){
      float4 xv = *(const float4*)&xs[tr*68 + k4*4];
      float4 w0 = *(const float4*)&wsb[(k4*4+0)*64 + tc*4];
      float4 w1 = *(const float4*)&wsb[(k4*4+1)*64 + tc*4];
      float4 w2 = *(const float4*)&wsb[(k4*4+2)*64 + tc*4];
      float4 w3 = *(const float4*)&wsb[(k4*4+3)*64 + tc*4];
      fma4(acc, xv.x, w0); fma4(acc, xv.y, w1);
      fma4(acc, xv.z, w2); fma4(acc, xv.w, w3);
    }
    float4 bb = *(const float4*)&bt[w][tc*4];
    *(float4*)&Ot[w][(row0+tr)*64 + tc*4] =
      make_float4(acc.x+bb.x, acc.y+bb.y, acc.z+bb.z, acc.w+bb.w);
  }
}

// ---------------------------------------------------------------------------
// Mega-fused: logits+softmax -> attn, Z=P@V, zo=Z@Wo+bo+x, LN1, FFN, LN2,
// R + pred.  Grid (80 bp, 10 chunks of 16 t) = 800 blocks.
// LDS 40.3KB -> 4 blocks/CU (16 waves/CU). K staged as packed bf16x2.
// ---------------------------------------------------------------------------
__global__ __launch_bounds__(256, 4) void k_attn_ffn(const float* __restrict__ Q,
    const float* __restrict__ Kout, const float* __restrict__ Vout,
    const float* __restrict__ Wo, const float* __restrict__ bo,
    const float* __restrict__ g1, const float* __restrict__ b1l,
    const float* __restrict__ x,
    const float* __restrict__ W1, const float* __restrict__ b1,
    const float* __restrict__ W2, const float* __restrict__ b2,
    const float* __restrict__ g2, const float* __restrict__ b2l,
    const float* __restrict__ Wf, const float* __restrict__ bf,
    float* __restrict__ attn, float* __restrict__ R,
    float* __restrict__ pred, float* __restrict__ predr){
  // union region: phaseA/B/C: ks2(21120B) | qs(4352B) | ps(10496B) = 35968B
  //               FFN:        as(16640B)  | red(16384B)           = 33024B
  __shared__ __align__(16) unsigned char smem[35968];
  __shared__ __align__(16) float os[16*68];           // LN1 out (residual)
  unsigned* ks2 = (unsigned*)smem;                    // 160 x 33 u32 (bf16x2)
  float* qs = (float*)(smem + 21120);                 // 16 x 68
  float* ps = (float*)(smem + 25472);                 // 16 x 164
  float* Zs  = qs;                                    // 16 x 68 (after phase A)
  float* zos = ps;                                    // 16 x 68 (after phase B)
  float* as  = (float*)smem;                          // 16 x 260 (FFN)
  float* red = (float*)(smem + 16640);                // 4096 (FFN split-K)

  int tid = threadIdx.x;
  int bp = blockIdx.x, c = blockIdx.y;
  int t0g = c*16, tend = t0g + 16;
  int ng = (tend + 63) >> 6;                          // 1..3 s-groups
  const float* Kb = Kout + bp*(SS*DD);
  const float* Vb = Vout + bp*(SS*DD);
  const float* Qb = Q + bp*(SS*DD);
  float* Ab = attn + bp*(SS*SS);

  // ---- stage K (packed bf16) + Q chunk ----
  for (int i = tid; i < tend*16; i += 256){
    int r = i >> 4, e4 = i & 15;
    float4 kv = *(const float4*)&Kb[r*64 + e4*4];
    int base = r*33 + e4*2;
    ks2[base]   = packbf2(kv.x, kv.y);
    ks2[base+1] = packbf2(kv.z, kv.w);
  }
  {
    int r = tid >> 4, e4 = (tid & 15)*4;
    *(float4*)&qs[r*68 + e4] = *(const float4*)&Qb[(t0g + r)*64 + e4];
  }
  __syncthreads();

  int lane = tid & 63, wid = tid >> 6;
  int s0 = lane, s1 = lane + 64, s2 = lane + 128;
  int a0 = s0*33, a1 = s1*33, a2 = (s2 < SS ? s2 : 0)*33;

  // ---- phase A: logits + softmax -> attn global + ps ----
  {
    float acc[4][3] = {};
#pragma unroll 4
    for (int e4 = 0; e4 < 16; ++e4){
      int e2 = e4*2;
      unsigned u00 = ks2[a0+e2], u01 = ks2[a0+e2+1];
      float k00 = bflo(u00), k01 = bfhi(u00), k02 = bflo(u01), k03 = bfhi(u01);
      float k10=0,k11=0,k12=0,k13=0,k20=0,k21=0,k22=0,k23=0;
      if (ng > 1){ unsigned u10 = ks2[a1+e2], u11 = ks2[a1+e2+1];
        k10 = bflo(u10); k11 = bfhi(u10); k12 = bflo(u11); k13 = bfhi(u11); }
      if (ng > 2){ unsigned u20 = ks2[a2+e2], u21 = ks2[a2+e2+1];
        k20 = bflo(u20); k21 = bfhi(u20); k22 = bflo(u21); k23 = bfhi(u21); }
#pragma unroll
      for (int tt = 0; tt < 4; ++tt){
        float4 q4 = *(const float4*)&qs[(wid*4+tt)*68 + e4*4];
        acc[tt][0] += q4.x*k00 + q4.y*k01 + q4.z*k02 + q4.w*k03;
        if (ng > 1) acc[tt][1] += q4.x*k10 + q4.y*k11 + q4.z*k12 + q4.w*k13;
        if (ng > 2) acc[tt][2] += q4.x*k20 + q4.y*k21 + q4.z*k22 + q4.w*k23;
      }
    }
#pragma unroll
    for (int tt = 0; tt < 4; ++tt){
      int lt = wid*4 + tt;
      int t = t0g + lt;
      bool v0 = (s0 <= t), v1 = (s1 <= t), v2 = (s2 <= t) && (s2 < SS);
      float l0 = v0 ? acc[tt][0]*0.125f : -INFINITY;
      float l1 = v1 ? acc[tt][1]*0.125f : -INFINITY;
      float l2 = v2 ? acc[tt][2]*0.125f : -INFINITY;
      float m = wred_max(fmaxf(l0, fmaxf(l1, l2)));
      float e0 = v0 ? __expf(l0-m) : 0.f;
      float e1 = v1 ? __expf(l1-m) : 0.f;
      float e2 = v2 ? __expf(l2-m) : 0.f;
      float inv = 1.0f / wred_sum(e0+e1+e2);
      float p0 = e0*inv, p1 = e1*inv, p2 = e2*inv;
      float* Arow = &Ab[t*SS];
      Arow[s0] = p0; ps[lt*164 + s0] = p0;
      Arow[s1] = p1; ps[lt*164 + s1] = p1;
      if (s2 < SS){ Arow[s2] = p2; ps[lt*164 + s2] = p2; }
    }
  }
  __syncthreads();

  // ---- phase B: Z(16x64) = P @ V (V from global/L2) ----
  int tc = tid & 15, tr = tid >> 4;
  {
    float4 z = make_float4(0.f,0.f,0.f,0.f);
    int pb = tr*164;
#pragma unroll 4
    for (int s = 0; s < tend; ++s){
      float p = ps[pb + s];
      float4 v4 = *(const float4*)&Vb[s*64 + tc*4];
      fma4(z, p, v4);
    }
    *(float4*)&Zs[tr*68 + tc*4] = z;
  }
  __syncthreads();

  // ---- phase C: zo = Z@Wo + bo + x ----
  {
    float4 acc = make_float4(0.f,0.f,0.f,0.f);
#pragma unroll 4
    for (int k4 = 0; k4 < 16; ++k4){
      float4 z4 = *(const float4*)&Zs[tr*68 + k4*4];
      float4 w0 = *(const float4*)&Wo[(k4*4+0)*64 + tc*4];
      float4 w1 = *(const float4*)&Wo[(k4*4+1)*64 + tc*4];
      float4 w2 = *(const float4*)&Wo[(k4*4+2)*64 + tc*4];
      float4 w3 = *(const float4*)&Wo[(k4*4+3)*64 + tc*4];
      fma4(acc, z4.x, w0); fma4(acc, z4.y, w1);
      fma4(acc, z4.z, w2); fma4(acc, z4.w, w3);
    }
    float4 bo4 = *(const float4*)&bo[tc*4];
    float4 xr  = *(const float4*)&x[(bp*SS + t0g + tr)*64 + tc*4];
    *(float4*)&zos[tr*68 + tc*4] = make_float4(acc.x+bo4.x+xr.x, acc.y+bo4.y+xr.y,
                                               acc.z+bo4.z+xr.z, acc.w+bo4.w+xr.w);
  }
  __syncthreads();

  // ---- LN1 -> os ----
  for (int r = wid; r < 16; r += 4){
    float h = zos[r*68 + lane];
    float mu = wred_sum(h) * (1.f/64.f);
    float dv = h - mu;
    float var = wred_sum(dv*dv) * (1.f/64.f);
    os[r*68 + lane] = g1[lane]*dv*rsqrtf(var + 1e-6f) + b1l[lane];
  }
  __syncthreads();

  // ---- FFN1: as = relu(os @ W1 + b1)  (16x256) ----
  {
    int fc = tid & 63, fr = tid >> 6;
    float4 acc[4];
#pragma unroll
    for (int i = 0; i < 4; ++i) acc[i] = make_float4(0.f,0.f,0.f,0.f);
#pragma unroll 2
    for (int k4 = 0; k4 < 16; ++k4){
      float4 a0 = *(const float4*)&os[(fr*4+0)*68 + k4*4];
      float4 a1 = *(const float4*)&os[(fr*4+1)*68 + k4*4];
      float4 a2 = *(const float4*)&os[(fr*4+2)*68 + k4*4];
      float4 a3 = *(const float4*)&os[(fr*4+3)*68 + k4*4];
      float4 w0 = *(const float4*)&W1[(k4*4+0)*256 + fc*4];
      float4 w1 = *(const float4*)&W1[(k4*4+1)*256 + fc*4];
      float4 w2 = *(const float4*)&W1[(k4*4+2)*256 + fc*4];
      float4 w3 = *(const float4*)&W1[(k4*4+3)*256 + fc*4];
      fma4(acc[0], a0.x, w0); fma4(acc[0], a0.y, w1); fma4(acc[0], a0.z, w2); fma4(acc[0], a0.w, w3);
      fma4(acc[1], a1.x, w0); fma4(acc[1], a1.y, w1); fma4(acc[1], a1.z, w2); fma4(acc[1], a1.w, w3);
      fma4(acc[2], a2.x, w0); fma4(acc[2], a2.y, w1); fma4(acc[2], a2.z, w2); fma4(acc[2], a2.w, w3);
      fma4(acc[3], a3.x, w0); fma4(acc[3], a3.y, w1); fma4(acc[3], a3.z, w2); fma4(acc[3], a3.w, w3);
    }
    float4 bb = *(const float4*)&b1[fc*4];
#pragma unroll
    for (int i = 0; i < 4; ++i)
      *(float4*)&as[(fr*4+i)*260 + fc*4] = make_float4(
        fmaxf(acc[i].x+bb.x,0.f), fmaxf(acc[i].y+bb.y,0.f),
        fmaxf(acc[i].z+bb.z,0.f), fmaxf(acc[i].w+bb.w,0.f));
  }
  __syncthreads();

  // ---- FFN2: 16x64, K=256 split-K x4 (one partition per wave) ----
  {
    int kp = wid;
    int tc2 = lane & 15, tr2 = lane >> 4;
    float4 acc[4];
#pragma unroll
    for (int i = 0; i < 4; ++i) acc[i] = make_float4(0.f,0.f,0.f,0.f);
    int kbase = kp*64;
#pragma unroll 2
    for (int kk4 = 0; kk4 < 16; ++kk4){
      int k = kbase + kk4*4;
      float4 a0 = *(const float4*)&as[(tr2*4+0)*260 + k];
      float4 a1 = *(const float4*)&as[(tr2*4+1)*260 + k];
      float4 a2 = *(const float4*)&as[(tr2*4+2)*260 + k];
      float4 a3 = *(const float4*)&as[(tr2*4+3)*260 + k];
      float4 w0 = *(const float4*)&W2[(k+0)*64 + tc2*4];
      float4 w1 = *(const float4*)&W2[(k+1)*64 + tc2*4];
      float4 w2 = *(const float4*)&W2[(k+2)*64 + tc2*4];
      float4 w3 = *(const float4*)&W2[(k+3)*64 + tc2*4];
      fma4(acc[0], a0.x, w0); fma4(acc[0], a0.y, w1); fma4(acc[0], a0.z, w2); fma4(acc[0], a0.w, w3);
      fma4(acc[1], a1.x, w0); fma4(acc[1], a1.y, w1); fma4(acc[1], a1.z, w2); fma4(acc[1], a1.w, w3);
      fma4(acc[2], a2.x, w0); fma4(acc[2], a2.y, w1); fma4(acc[2], a2.z, w2); fma4(acc[2], a2.w, w3);
      fma4(acc[3], a3.x, w0); fma4(acc[3], a3.y, w1); fma4(acc[3], a3.z, w2); fma4(acc[3], a3.w, w3);
    }
#pragma unroll
    for (int i = 0; i < 4; ++i)
      *(float4*)&red[kp*1024 + (tr2*4+i)*64 + tc2*4] = acc[i];
  }
  __syncthreads();

  // ---- reduce + residual + LN2 -> R, pred ----
  {
    float wfv = Wf[lane];
    float bfv = bf[0];
#pragma unroll
    for (int j = 0; j < 4; ++j){
      int r = wid*4 + j;
      float h = red[r*64+lane] + red[1024 + r*64+lane]
              + red[2048 + r*64+lane] + red[3072 + r*64+lane]
              + b2[lane] + os[r*68 + lane];
      float mu = wred_sum(h) * (1.f/64.f);
      float dv = h - mu;
      float var = wred_sum(dv*dv) * (1.f/64.f);
      float rv = g2[lane]*dv*rsqrtf(var + 1e-6f) + b2l[lane];
      int grow = bp*SS + t0g + r;
      R[grow*64 + lane] = rv;
      float pw = wred_sum(rv * wfv);
      if (lane == 0){ pred[grow] = pw + bfv; predr[grow] = pw + bfv; }
    }
  }
}

extern "C" void kernel_launch(void* const* d_in, const int* in_sizes, int n_in,
                              void* d_out, int out_size, void* d_ws, size_t ws_size,
                              hipStream_t stream){
  const float* inputs = (const float*)d_in[0];
  const float* Wp  = (const float*)d_in[2];
  const float* bpj = (const float*)d_in[3];
  const float* Wq  = (const float*)d_in[4];  const float* bq  = (const float*)d_in[5];
  const float* Wk  = (const float*)d_in[6];  const float* bk  = (const float*)d_in[7];
  const float* Wv  = (const float*)d_in[8];  const float* bv  = (const float*)d_in[9];
  const float* Wo  = (const float*)d_in[10]; const float* bo  = (const float*)d_in[11];
  const float* g1  = (const float*)d_in[12]; const float* b1l = (const float*)d_in[13];
  const float* W1  = (const float*)d_in[14]; const float* b1  = (const float*)d_in[15];
  const float* W2  = (const float*)d_in[16]; const float* b2  = (const float*)d_in[17];
  const float* g2  = (const float*)d_in[18]; const float* b2l = (const float*)d_in[19];
  const float* Wf  = (const float*)d_in[20]; const float* bf  = (const float*)d_in[21];

  float* outp = (float*)d_out;
  float* ws   = (float*)d_ws;
  float* x    = ws;                 // 819200 floats
  float* Qw   = ws + 819200;        // 819200

  float* pred  = outp + OFF_PRED;
  float* predr = outp + OFF_PREDR;
  float* Kc    = outp + OFF_K;
  float* Vc    = outp + OFF_V;
  float* Rr    = outp + OFF_R;
  float* attn  = outp + OFF_ATTN;

  k_xqkv<<<NROW/16, 256, 0, stream>>>(inputs, Wp, bpj, Wq, bq, Wk, bk, Wv, bv,
                                      x, Qw, Kc, Vc);
  k_attn_ffn<<<dim3(NBP, 10), 256, 0, stream>>>(Qw, Kc, Vc, Wo, bo, g1, b1l, x,
                                                W1, b1, W2, b2, g2, b2l, Wf, bf,
                                                attn, Rr, pred, predr);
}